// Round 2
// baseline (133.561 us; speedup 1.0000x reference)
//
#include <hip/hip_runtime.h>

#define NNODES 163842
#define INF 32
#define OUTF 32
#define KTOT (7 * INF)   // 224

// Transpose W [32, 224] row-major -> Wt [224, 32] so the main kernel's
// wave-uniform W reads are contiguous (s_load_dwordx16-friendly).
__global__ void transpose_W_kernel(const float* __restrict__ W,
                                   float* __restrict__ Wt) {
    int i = blockIdx.x * blockDim.x + threadIdx.x;
    if (i < KTOT * OUTF) {
        int k = i / OUTF;
        int o = i % OUTF;
        Wt[k * OUTF + o] = W[o * KTOT + k];
    }
}

__global__ __launch_bounds__(256) void onering_conv_kernel(
    const float* __restrict__ x,
    const int* __restrict__ idx,
    const float* __restrict__ Wt,
    const float* __restrict__ b,
    float* __restrict__ out) {
    int n = blockIdx.x * 256 + threadIdx.x;
    bool valid = (n < NNODES);
    int nc = valid ? n : (NNODES - 1);   // clamp; tail lanes compute garbage, don't store

    // 7 neighbor indices for this node (coalesced-ish: 28B/lane contiguous)
    int ib[7];
    int base = nc * 7;
#pragma unroll
    for (int j = 0; j < 7; ++j) ib[j] = idx[base + j];

    // accumulators init with bias (wave-uniform -> scalar loads)
    float acc[OUTF];
#pragma unroll
    for (int o = 0; o < OUTF; ++o) acc[o] = b[o];

    // prefetch row 0
    float4 buf0[8], buf1[8];
    {
        const float4* rp = (const float4*)(x + (size_t)ib[0] * INF);
#pragma unroll
        for (int q = 0; q < 8; ++q) buf0[q] = rp[q];
    }

#pragma unroll
    for (int j = 0; j < 7; ++j) {
        float4* curb = (j & 1) ? buf1 : buf0;
        float4* nxtb = (j & 1) ? buf0 : buf1;
        if (j < 6) {
            const float4* np = (const float4*)(x + (size_t)ib[j + 1] * INF);
#pragma unroll
            for (int q = 0; q < 8; ++q) nxtb[q] = np[q];
        }
        const float* xr = (const float*)curb;
#pragma unroll
        for (int f = 0; f < INF; ++f) {
            float xv = xr[f];
            // Wt index is compile-time constant offset -> wave-uniform -> SGPR
            const float* wrow = Wt + (j * INF + f) * OUTF;
#pragma unroll
            for (int o = 0; o < OUTF; ++o) {
                acc[o] = fmaf(xv, wrow[o], acc[o]);
            }
        }
    }

    if (valid) {
        float4* op = (float4*)(out + (size_t)n * OUTF);
#pragma unroll
        for (int q = 0; q < 8; ++q) {
            op[q] = *((float4*)&acc[q * 4]);
        }
    }
}

extern "C" void kernel_launch(void* const* d_in, const int* in_sizes, int n_in,
                              void* d_out, int out_size, void* d_ws, size_t ws_size,
                              hipStream_t stream) {
    const float* x   = (const float*)d_in[0];
    const int*   idx = (const int*)d_in[1];
    const float* W   = (const float*)d_in[2];
    const float* b   = (const float*)d_in[3];
    float* out = (float*)d_out;
    float* Wt  = (float*)d_ws;   // 224*32 floats = 28 KB

    transpose_W_kernel<<<(KTOT * OUTF + 255) / 256, 256, 0, stream>>>(W, Wt);

    int grid = (NNODES + 255) / 256;  // 641
    onering_conv_kernel<<<grid, 256, 0, stream>>>(x, idx, Wt, b, out);
}